// Round 4
// baseline (535.274 us; speedup 1.0000x reference)
//
#include <hip/hip_runtime.h>

// FourierBlock: per (b, c): rfft(4096) -> keep top-16 |X| bins -> irfft.
//
// Round 7: SINGLE fused kernel. Round-3 accounting showed the separate
// synth kernel cost ~204 us invariant across three different inner-loop
// structures (VALU roofline ~25 us) -> its cost is launch/dependency/
// small-block structure, not math. So synthesis moves into the FFT kernel's
// tail, where 4 of 8 waves were idle during top-k anyway:
//   - after top-16, coeff-writer lanes drop (a, b, cos/sin of the stride-512
//     step) per bin into 1.3 KB of LDS,
//   - all 512 threads synthesize the block's own 4 channels: 8 samples
//     (l = tid + 512k) x 4 ch x 16 bins, Chebyshev recurrence with step 512
//     (T = 2 cos(2 pi f/8)); only 2 trans ops per sinusoid per thread,
//   - per-channel partials staged through the dead spectrum LDS (keeps live
//     VGPRs ~75; no spill risk at the (512,2) bound),
//   - stores mirror the input loads: strided float4 out[b, l, 4q..4q+3];
//     the XCD-contiguous remap makes the 32 sibling blocks of a batch merge
//     their partial 128B lines in one XCD's L2 -> full-line writebacks.
// The W coeff buffer, second kernel, and its launch overhead are deleted.

#define SWZ(i) ((i) ^ (((i) >> 4) & 15))

__device__ __forceinline__ int drev16(int x) {
  // reverse the three base-16 digits of a 12-bit index (involution)
  return ((x & 15) << 8) | (x & 0xF0) | ((x >> 8) & 15);
}

__device__ __forceinline__ float2 cmulf(float2 a, float c, float s) {
  return make_float2(a.x * c - a.y * s, a.x * s + a.y * c);
}

__device__ __forceinline__ void bfly4(float2& a0, float2& a1, float2& a2, float2& a3) {
  float ar = a0.x + a2.x, ai = a0.y + a2.y;
  float br = a0.x - a2.x, bi = a0.y - a2.y;
  float cr = a1.x + a3.x, ci = a1.y + a3.y;
  float dr = a1.x - a3.x, di = a1.y - a3.y;
  a0 = make_float2(ar + cr, ai + ci);
  a1 = make_float2(br + di, bi - dr);   // b - i*d
  a2 = make_float2(ar - cr, ai - ci);
  a3 = make_float2(br - di, bi + dr);   // b + i*d
}

// 16-point DIF DFT in registers; output slot s holds bin rev4(s).
__device__ __forceinline__ void dft16(float2* v) {
  const float C16[10] = {1.f, 0.9238795325112867f, 0.7071067811865476f, 0.3826834323650898f, 0.f,
                         -0.3826834323650898f, -0.7071067811865476f, -0.9238795325112867f, -1.f,
                         -0.9238795325112867f};
  const float S16[10] = {0.f, -0.3826834323650898f, -0.7071067811865476f, -0.9238795325112867f, -1.f,
                         -0.9238795325112867f, -0.7071067811865476f, -0.3826834323650898f, 0.f,
                         0.3826834323650898f};
  #pragma unroll
  for (int j2 = 0; j2 < 4; j2++) {
    bfly4(v[j2], v[j2 + 4], v[j2 + 8], v[j2 + 12]);
    if (j2 > 0) {
      v[j2 + 4]  = cmulf(v[j2 + 4],  C16[j2],     S16[j2]);
      v[j2 + 8]  = cmulf(v[j2 + 8],  C16[2 * j2], S16[2 * j2]);
      v[j2 + 12] = cmulf(v[j2 + 12], C16[3 * j2], S16[3 * j2]);
    }
  }
  #pragma unroll
  for (int r2 = 0; r2 < 4; r2++) bfly4(v[4 * r2], v[4 * r2 + 1], v[4 * r2 + 2], v[4 * r2 + 3]);
}

// One radix-16 DIF pass over a span; M = twiddle span (0 = last pass, none).
// Twiddle angle is a/M revolutions, a in [0, M): exact fp32, already in
// [0,1) -> feed v_sin/v_cos (period-1 hardware trig) directly.
template <int STRIDE, int M>
__device__ __forceinline__ void fft_pass(float2* Zl, int base, int j) {
  const int kRev4[16] = {0, 4, 8, 12, 1, 5, 9, 13, 2, 6, 10, 14, 3, 7, 11, 15};
  float2 v[16];
  #pragma unroll
  for (int p = 0; p < 16; p++) v[p] = Zl[SWZ(base + j + STRIDE * p)];
  dft16(v);
  #pragma unroll
  for (int r = 0; r < 16; r++) {
    float2 u = v[kRev4[r]];
    if (M > 0 && r > 0) {
      int a = (j * r) & (M - 1);
      float x = (float)a * (1.0f / (float)M);       // revolutions, exact
      float s = -__builtin_amdgcn_sinf(x);          // e^{-2pi i x}
      float c =  __builtin_amdgcn_cosf(x);
      u = cmulf(u, c, s);
    }
    Zl[SWZ(base + j + STRIDE * r)] = u;
  }
}

// ---------------- fused FFT + top-k + synthesis kernel ---------------------

__global__ __launch_bounds__(512, 2) void fourier_fused(
    const float4* __restrict__ X4, float4* __restrict__ O4) {
  __shared__ float2 Z[2][4096];     // spectrum workspace; reused for partials
  __shared__ float4 CF[64];         // [lc*16+j] = (a, b, cos_step, sin_step)
  __shared__ float  CFf[64];        // bin frequency f

  const int tid = threadIdx.x;
  // XCD-contiguous remap (bijective: 2048 blocks, 8 XCDs, 256 each):
  // XCD k gets original ids [256k, 256k+256) -> 8 whole batches per XCD,
  // so all 32 q-siblings of a batch share that XCD's L2 lines (reads AND
  // partial-line writes).
  const int o = ((blockIdx.x & 7) << 8) + (blockIdx.x >> 3);
  const int b = o >> 5;
  const int q = o & 31;             // 4-channel group

  // ---- load: x[b, l, 4q..4q+3] is one float4; (ch0,ch1)->Z0, (ch2,ch3)->Z1
  const float4* src = X4 + (size_t)b * 4096 * 32 + q;
  #pragma unroll
  for (int k = 0; k < 8; k++) {
    int l = tid + 512 * k;
    float4 v = src[(size_t)l * 32];
    Z[0][SWZ(l)] = make_float2(v.x, v.y);
    Z[1][SWZ(l)] = make_float2(v.z, v.w);
  }
  __syncthreads();

  const int h = tid >> 8;      // half: 0 -> Z[0], 1 -> Z[1]
  const int lt = tid & 255;    // thread id within half
  float2* Zl = Z[h];

  // ---- forward FFT (3 radix-16 passes), output hex-digit-reversed ----
  fft_pass<256, 4096>(Zl, 0, lt);
  __syncthreads();
  fft_pass<16, 256>(Zl, (lt >> 4) << 8, lt & 15);
  __syncthreads();
  fft_pass<1, 0>(Zl, lt << 4, 0);
  __syncthreads();

  // ---- top-16 selection: wave 0 of half = even channel, wave 1 = odd ----
  const int wv = lt >> 6;      // wave within half
  const int lane = lt & 63;

  if (wv < 2) {
    const int ch = wv;
    int rF = 0; float rA = 0.f, rB = 0.f;   // captured winner (lanes 0..15)
    float m2[32];
    #pragma unroll
    for (int k = 0; k < 32; k++) {
      int f = lane + (k << 6);
      float2 P = Zl[SWZ(drev16(f))];
      float2 Q = Zl[SWZ(drev16((4096 - f) & 4095))];
      float xr = ch ? (P.y + Q.y) : (P.x + Q.x);
      float xi = ch ? (Q.x - P.x) : (P.y - Q.y);
      m2[k] = xr * xr + xi * xi;   // 4*|X|^2 (uniform scale, ordering only)
    }
    float m2x = -1.f;              // bin f=2048 (Nyquist), lane 0 only
    if (lane == 0) {
      float2 P = Zl[SWZ(8)];       // drev16(2048) == 8
      float t = ch ? P.y : P.x;
      m2x = 4.f * t * t;
    }
    for (int r = 0; r < 16; r++) {
      float bv = -1e30f; int bf = 0;
      #pragma unroll
      for (int k = 0; k < 32; k++) {
        int f = lane + (k << 6);
        if (m2[k] > bv) { bv = m2[k]; bf = f; }   // ascending k: ties -> lower f
      }
      if (m2x > bv) { bv = m2x; bf = 2048; }
      #pragma unroll
      for (int off = 32; off; off >>= 1) {
        float ov = __shfl_down(bv, off);
        int   of = __shfl_down(bf, off);
        if (ov > bv || (ov == bv && of < bf)) { bv = ov; bf = of; }
      }
      bf = __shfl(bf, 0);          // broadcast winner bin
      if (lane == r) {             // capture X[bf] in lane r's registers
        rF = bf;
        float2 P = Zl[SWZ(drev16(bf))];
        float2 Q = Zl[SWZ(drev16((4096 - bf) & 4095))];
        rA = ch ? 0.5f * (P.y + Q.y) : 0.5f * (P.x + Q.x);
        rB = ch ? 0.5f * (Q.x - P.x) : 0.5f * (P.y - Q.y);
      }
      if (bf == 2048) {
        if (lane == 0) m2x = -2.f;
      } else if ((bf & 63) == lane) {
        int kk = bf >> 6;
        #pragma unroll
        for (int k = 0; k < 32; k++) if (k == kk) m2[k] = -2.f;
      }
    }

    // ---- publish coefficients + stride-512 step constants to LDS.
    //      out[l] = sum alpha*cos(2 pi f l/4096) + beta*sin(...), with
    //      alpha = w*Re(X), beta = -w*Im(X), w = 1/N (f=0,2048) else 2/N.
    //      Step angle f*512/4096 = f/8 rev (exact fp32).
    if (lane < 16) {
      const float inv = 2.44140625e-4f;            // 1/4096
      float w = (rF == 0 || rF == 2048) ? inv : 2.f * inv;
      float fv = (float)rF;
      float dx = fv * 0.125f;
      dx -= floorf(dx);
      float cd = __builtin_amdgcn_cosf(dx);
      float sd = __builtin_amdgcn_sinf(dx);
      int lc = 2 * h + wv;                         // local channel 0..3
      CF[lc * 16 + lane] = make_float4(w * rA, -w * rB, cd, sd);
      CFf[lc * 16 + lane] = fv;
    }
  }
  __syncthreads();   // spectrum dead; CF/CFf valid; Z reusable as partials

  // ---- synthesis: thread owns samples l = tid + 512k, k = 0..7, all 4 ch.
  // Chebyshev: g(l+512) = T g(l) - g(l-512), T = 2 cos(2 pi f/8).
  // x0 = f*tid/4096 rev exact (f*tid <= 2048*511 < 2^23). Per-channel
  // partials go through the dead spectrum LDS (same-thread addresses, no
  // barrier needed) to keep live VGPRs low.
  float* S = (float*)Z;              // 16384 floats = 4 channels x 4096
  const float tf = (float)tid;
  #pragma unroll
  for (int cc = 0; cc < 4; cc++) {
    float u[16], v[16], T[16];
    #pragma unroll
    for (int j = 0; j < 16; j++) {
      float4 cf = CF[cc * 16 + j];
      float f  = CFf[cc * 16 + j];
      float x0 = f * tf * 2.44140625e-4f;
      x0 -= floorf(x0);
      float c0 = __builtin_amdgcn_cosf(x0);
      float s0 = __builtin_amdgcn_sinf(x0);
      float G = fmaf(cf.x, c0, cf.y * s0);    // g(tid)
      float H = fmaf(cf.y, c0, -cf.x * s0);   // b cos - a sin
      u[j] = G;
      v[j] = fmaf(G, cf.z, -H * cf.w);        // g(tid - 512)
      T[j] = cf.z + cf.z;
    }
    #pragma unroll
    for (int k = 0; k < 8; k += 2) {
      float s0a = 0.f, s1a = 0.f;
      #pragma unroll
      for (int j = 0; j < 16; j++) {
        s0a += u[j];
        v[j] = fmaf(T[j], u[j], -v[j]);       // v <- g(l + 512)
      }
      #pragma unroll
      for (int j = 0; j < 16; j++) {
        s1a += v[j];
        u[j] = fmaf(T[j], v[j], -u[j]);       // u <- g(l + 1024)
      }
      S[cc * 4096 + tid + 512 * k]       = s0a;
      S[cc * 4096 + tid + 512 * (k + 1)] = s1a;
    }
  }

  // ---- store: float4 = 4 channels at one sample, mirror of the load ----
  float4* dst = O4 + (size_t)b * 4096 * 32 + q;
  #pragma unroll
  for (int k = 0; k < 8; k++) {
    int l = tid + 512 * k;
    dst[(size_t)l * 32] =
        make_float4(S[l], S[4096 + l], S[8192 + l], S[12288 + l]);
  }
}

extern "C" void kernel_launch(void* const* d_in, const int* in_sizes, int n_in,
                              void* d_out, int out_size, void* d_ws, size_t ws_size,
                              hipStream_t stream) {
  (void)in_sizes; (void)n_in; (void)ws_size; (void)out_size; (void)d_ws;
  const float4* x = (const float4*)d_in[0];
  float4* out = (float4*)d_out;

  fourier_fused<<<dim3(64 * 32), dim3(512), 0, stream>>>(x, out);
}

// Round 5
// 504.749 us; speedup vs baseline: 1.0605x; 1.0605x over previous
//
#include <hip/hip_runtime.h>

// FourierBlock: per (b, c): rfft(4096) -> keep top-16 |X| bins -> irfft.
//
// Round 8: same fused single-kernel algorithm as round 7, but the block is
// HALVED: 256 threads / 2 channels / one complex FFT, LDS 33 KB -> 4 blocks
// per CU (was 2 x 512-thread blocks at 67 KB). Round-7 counters showed a
// latency-bound kernel (VALUBusy 36%, occupancy 22.6%, arithmetic ~10 us,
// HBM ~40 us, dur 389 us): too few independent instruction streams per CU.
// 4 independent barrier groups of 4 waves overlap each other's load
// latency / barrier drains. Per-thread work is unchanged; loads/stores are
// strided float2 (same cacheline count as float4, 2x instructions); the
// XCD-contiguous remap extends to 4096 blocks (512/XCD, bijective) so the
// ~32 concurrently-resident sibling blocks of a batch merge lines in one
// XCD's L2 for both reads and partial-line writes.

#define SWZ(i) ((i) ^ (((i) >> 4) & 15))

__device__ __forceinline__ int drev16(int x) {
  // reverse the three base-16 digits of a 12-bit index (involution)
  return ((x & 15) << 8) | (x & 0xF0) | ((x >> 8) & 15);
}

__device__ __forceinline__ float2 cmulf(float2 a, float c, float s) {
  return make_float2(a.x * c - a.y * s, a.x * s + a.y * c);
}

__device__ __forceinline__ void bfly4(float2& a0, float2& a1, float2& a2, float2& a3) {
  float ar = a0.x + a2.x, ai = a0.y + a2.y;
  float br = a0.x - a2.x, bi = a0.y - a2.y;
  float cr = a1.x + a3.x, ci = a1.y + a3.y;
  float dr = a1.x - a3.x, di = a1.y - a3.y;
  a0 = make_float2(ar + cr, ai + ci);
  a1 = make_float2(br + di, bi - dr);   // b - i*d
  a2 = make_float2(ar - cr, ai - ci);
  a3 = make_float2(br - di, bi + dr);   // b + i*d
}

// 16-point DIF DFT in registers; output slot s holds bin rev4(s).
__device__ __forceinline__ void dft16(float2* v) {
  const float C16[10] = {1.f, 0.9238795325112867f, 0.7071067811865476f, 0.3826834323650898f, 0.f,
                         -0.3826834323650898f, -0.7071067811865476f, -0.9238795325112867f, -1.f,
                         -0.9238795325112867f};
  const float S16[10] = {0.f, -0.3826834323650898f, -0.7071067811865476f, -0.9238795325112867f, -1.f,
                         -0.9238795325112867f, -0.7071067811865476f, -0.3826834323650898f, 0.f,
                         0.3826834323650898f};
  #pragma unroll
  for (int j2 = 0; j2 < 4; j2++) {
    bfly4(v[j2], v[j2 + 4], v[j2 + 8], v[j2 + 12]);
    if (j2 > 0) {
      v[j2 + 4]  = cmulf(v[j2 + 4],  C16[j2],     S16[j2]);
      v[j2 + 8]  = cmulf(v[j2 + 8],  C16[2 * j2], S16[2 * j2]);
      v[j2 + 12] = cmulf(v[j2 + 12], C16[3 * j2], S16[3 * j2]);
    }
  }
  #pragma unroll
  for (int r2 = 0; r2 < 4; r2++) bfly4(v[4 * r2], v[4 * r2 + 1], v[4 * r2 + 2], v[4 * r2 + 3]);
}

// One radix-16 DIF pass over a span; M = twiddle span (0 = last pass, none).
// Twiddle angle is a/M revolutions, a in [0, M): exact fp32, already in
// [0,1) -> feed v_sin/v_cos (period-1 hardware trig) directly.
template <int STRIDE, int M>
__device__ __forceinline__ void fft_pass(float2* Zl, int base, int j) {
  const int kRev4[16] = {0, 4, 8, 12, 1, 5, 9, 13, 2, 6, 10, 14, 3, 7, 11, 15};
  float2 v[16];
  #pragma unroll
  for (int p = 0; p < 16; p++) v[p] = Zl[SWZ(base + j + STRIDE * p)];
  dft16(v);
  #pragma unroll
  for (int r = 0; r < 16; r++) {
    float2 u = v[kRev4[r]];
    if (M > 0 && r > 0) {
      int a = (j * r) & (M - 1);
      float x = (float)a * (1.0f / (float)M);       // revolutions, exact
      float s = -__builtin_amdgcn_sinf(x);          // e^{-2pi i x}
      float c =  __builtin_amdgcn_cosf(x);
      u = cmulf(u, c, s);
    }
    Zl[SWZ(base + j + STRIDE * r)] = u;
  }
}

// ---------------- fused FFT + top-k + synthesis kernel ---------------------

__global__ __launch_bounds__(256, 4) void fourier_fused(
    const float2* __restrict__ X2, float2* __restrict__ O2) {
  __shared__ float2 Z[4096];        // spectrum workspace; reused for partials
  __shared__ float4 CF[32];         // [ch*16+j] = (a, b, cos_step, sin_step)
  __shared__ float  CFf[32];        // bin frequency f

  const int tid = threadIdx.x;
  // XCD-contiguous remap (bijective: 4096 blocks, 8 XCDs, 512 each):
  // XCD k gets original ids [512k, 512k+512) -> 8 whole batches per XCD,
  // so concurrently-resident sibling blocks of a batch share that XCD's
  // L2 lines (reads AND partial-line writes).
  const int o = ((blockIdx.x & 7) << 9) + (blockIdx.x >> 3);
  const int b = o >> 6;
  const int q = o & 63;             // channel pair: channels 2q, 2q+1

  // ---- load: x[b, l, 2q..2q+1] is one float2 -> Z (ch0 = re, ch1 = im)
  const float2* src = X2 + (size_t)b * 4096 * 64 + q;
  #pragma unroll
  for (int k = 0; k < 16; k++) {
    int l = tid + 256 * k;
    Z[SWZ(l)] = src[(size_t)l * 64];
  }
  __syncthreads();

  // ---- forward FFT (3 radix-16 passes), output hex-digit-reversed ----
  fft_pass<256, 4096>(Z, 0, tid);
  __syncthreads();
  fft_pass<16, 256>(Z, (tid >> 4) << 8, tid & 15);
  __syncthreads();
  fft_pass<1, 0>(Z, tid << 4, 0);
  __syncthreads();

  // ---- top-16 selection: wave 0 = channel 2q, wave 1 = channel 2q+1 ----
  const int wv = tid >> 6;
  const int lane = tid & 63;

  if (wv < 2) {
    const int ch = wv;
    int rF = 0; float rA = 0.f, rB = 0.f;   // captured winner (lanes 0..15)
    float m2[32];
    #pragma unroll
    for (int k = 0; k < 32; k++) {
      int f = lane + (k << 6);
      float2 P = Z[SWZ(drev16(f))];
      float2 Q = Z[SWZ(drev16((4096 - f) & 4095))];
      float xr = ch ? (P.y + Q.y) : (P.x + Q.x);
      float xi = ch ? (Q.x - P.x) : (P.y - Q.y);
      m2[k] = xr * xr + xi * xi;   // 4*|X|^2 (uniform scale, ordering only)
    }
    float m2x = -1.f;              // bin f=2048 (Nyquist), lane 0 only
    if (lane == 0) {
      float2 P = Z[SWZ(8)];        // drev16(2048) == 8
      float t = ch ? P.y : P.x;
      m2x = 4.f * t * t;
    }
    for (int r = 0; r < 16; r++) {
      float bv = -1e30f; int bf = 0;
      #pragma unroll
      for (int k = 0; k < 32; k++) {
        int f = lane + (k << 6);
        if (m2[k] > bv) { bv = m2[k]; bf = f; }   // ascending k: ties -> lower f
      }
      if (m2x > bv) { bv = m2x; bf = 2048; }
      #pragma unroll
      for (int off = 32; off; off >>= 1) {
        float ov = __shfl_down(bv, off);
        int   of = __shfl_down(bf, off);
        if (ov > bv || (ov == bv && of < bf)) { bv = ov; bf = of; }
      }
      bf = __shfl(bf, 0);          // broadcast winner bin
      if (lane == r) {             // capture X[bf] in lane r's registers
        rF = bf;
        float2 P = Z[SWZ(drev16(bf))];
        float2 Q = Z[SWZ(drev16((4096 - bf) & 4095))];
        rA = ch ? 0.5f * (P.y + Q.y) : 0.5f * (P.x + Q.x);
        rB = ch ? 0.5f * (Q.x - P.x) : 0.5f * (P.y - Q.y);
      }
      if (bf == 2048) {
        if (lane == 0) m2x = -2.f;
      } else if ((bf & 63) == lane) {
        int kk = bf >> 6;
        #pragma unroll
        for (int k = 0; k < 32; k++) if (k == kk) m2[k] = -2.f;
      }
    }

    // ---- publish coefficients + stride-256 step constants to LDS.
    //      out[l] = sum alpha*cos(2 pi f l/4096) + beta*sin(...), with
    //      alpha = w*Re(X), beta = -w*Im(X), w = 1/N (f=0,2048) else 2/N.
    //      Step angle f*256/4096 = f/16 rev (exact fp32).
    if (lane < 16) {
      const float inv = 2.44140625e-4f;            // 1/4096
      float w = (rF == 0 || rF == 2048) ? inv : 2.f * inv;
      float fv = (float)rF;
      float dx = fv * 0.0625f;
      dx -= floorf(dx);
      float cd = __builtin_amdgcn_cosf(dx);
      float sd = __builtin_amdgcn_sinf(dx);
      CF[ch * 16 + lane] = make_float4(w * rA, -w * rB, cd, sd);
      CFf[ch * 16 + lane] = fv;
    }
  }
  __syncthreads();   // spectrum dead; CF/CFf valid; Z reusable as partials

  // ---- synthesis: thread owns samples l = tid + 256k, k = 0..15, 2 ch.
  // Chebyshev: g(l+256) = T g(l) - g(l-256), T = 2 cos(2 pi f/16).
  // x0 = f*tid/4096 rev exact (f*tid <= 2048*255 < 2^19). Per-channel
  // partials go through the dead spectrum LDS (same-thread addresses, no
  // barrier needed) to keep live VGPRs low (48 state regs per channel).
  float* S = (float*)Z;              // 8192 floats = 2 channels x 4096
  const float tf = (float)tid;
  #pragma unroll
  for (int cc = 0; cc < 2; cc++) {
    float u[16], v[16], T[16];
    #pragma unroll
    for (int j = 0; j < 16; j++) {
      float4 cf = CF[cc * 16 + j];
      float f  = CFf[cc * 16 + j];
      float x0 = f * tf * 2.44140625e-4f;
      x0 -= floorf(x0);
      float c0 = __builtin_amdgcn_cosf(x0);
      float s0 = __builtin_amdgcn_sinf(x0);
      float G = fmaf(cf.x, c0, cf.y * s0);    // g(tid)
      float H = fmaf(cf.y, c0, -cf.x * s0);   // b cos - a sin
      u[j] = G;
      v[j] = fmaf(G, cf.z, -H * cf.w);        // g(tid - 256)
      T[j] = cf.z + cf.z;
    }
    #pragma unroll
    for (int k = 0; k < 16; k += 2) {
      float s0a = 0.f, s1a = 0.f;
      #pragma unroll
      for (int j = 0; j < 16; j++) {
        s0a += u[j];
        v[j] = fmaf(T[j], u[j], -v[j]);       // v <- g(l + 256)
      }
      #pragma unroll
      for (int j = 0; j < 16; j++) {
        s1a += v[j];
        u[j] = fmaf(T[j], v[j], -u[j]);       // u <- g(l + 512)
      }
      S[cc * 4096 + tid + 256 * k]       = s0a;
      S[cc * 4096 + tid + 256 * (k + 1)] = s1a;
    }
  }

  // ---- store: float2 = 2 channels at one sample, mirror of the load ----
  float2* dst = O2 + (size_t)b * 4096 * 64 + q;
  #pragma unroll
  for (int k = 0; k < 16; k++) {
    int l = tid + 256 * k;
    dst[(size_t)l * 64] = make_float2(S[l], S[4096 + l]);
  }
}

extern "C" void kernel_launch(void* const* d_in, const int* in_sizes, int n_in,
                              void* d_out, int out_size, void* d_ws, size_t ws_size,
                              hipStream_t stream) {
  (void)in_sizes; (void)n_in; (void)ws_size; (void)out_size; (void)d_ws;
  const float2* x = (const float2*)d_in[0];
  float2* out = (float2*)d_out;

  fourier_fused<<<dim3(64 * 64), dim3(256), 0, stream>>>(x, out);
}